// Round 12
// baseline (615.481 us; speedup 1.0000x reference)
//
#include <hip/hip_runtime.h>
#include <math.h>

#define KE_C     14.3996f
#define ALPHA_C  0.3f
#define CUTOFF_C 10.0f
#define TWO_PI_C 6.283185307179586f
#define NK2      512           // padded half-k slot count (510 real)
#define NRB      256           // recip prelude blocks (64 mol x 4 chunks)
#define NREAL    2048          // mega grid (8 blocks/CU)
#define NAP      400           // SIpart stride (>= NA)

typedef float vfloat4 __attribute__((ext_vector_type(4)));
typedef int   vint4   __attribute__((ext_vector_type(4)));

__device__ __forceinline__ void sincos_rev(float x, float* s, float* c) {
    float f = __builtin_amdgcn_fractf(x);
    *s = __builtin_amdgcn_sinf(f);
    *c = __builtin_amdgcn_cosf(f);
}

__device__ __forceinline__ float inv3x3(const float* c, float* inv) {
    float a00 = c[0], a01 = c[1], a02 = c[2];
    float a10 = c[3], a11 = c[4], a12 = c[5];
    float a20 = c[6], a21 = c[7], a22 = c[8];
    float det = a00 * (a11 * a22 - a12 * a21)
              - a01 * (a10 * a22 - a12 * a20)
              + a02 * (a10 * a21 - a11 * a20);
    float id = 1.0f / det;
    inv[0] = (a11 * a22 - a12 * a21) * id;
    inv[1] = (a02 * a21 - a01 * a22) * id;
    inv[2] = (a01 * a12 - a02 * a11) * id;
    inv[3] = (a12 * a20 - a10 * a22) * id;
    inv[4] = (a00 * a22 - a02 * a20) * id;
    inv[5] = (a02 * a10 - a00 * a12) * id;
    inv[6] = (a10 * a21 - a11 * a20) * id;
    inv[7] = (a01 * a20 - a00 * a21) * id;
    inv[8] = (a00 * a11 - a01 * a10) * id;
    return det;
}

__device__ __forceinline__ float load_agent(const float* p) {
    return __hip_atomic_load(p, __ATOMIC_RELAXED, __HIP_MEMORY_SCOPE_AGENT);
}

// ---------------- setup: atoms + bounds + half-k + zeroing (no memset needed) ----------------
__global__ __launch_bounds__(256) void k_setup(const float* __restrict__ R,
                                               const float* __restrict__ q,
                                               const int* __restrict__ idx_m,
                                               const float* __restrict__ cell,
                                               const float* __restrict__ kvecs,
                                               float4* __restrict__ S4,
                                               float2* __restrict__ QM,
                                               float* __restrict__ SIpart,
                                               int* __restrict__ bounds,
                                               float4* __restrict__ KH,
                                               int* __restrict__ cnt,
                                               int* __restrict__ ticket,
                                               float* __restrict__ QR,
                                               float* __restrict__ QI,
                                               float* __restrict__ YRpad,
                                               int natoms, int nmol, int nk, int NA) {
    int bid = blockIdx.x;
    int tid = threadIdx.x;
    if (bid < NA) {
        __shared__ float si[64];
        if (tid < 64) si[tid] = 0.0f;
        __syncthreads();
        int a = bid * 256 + tid;
        if (a < natoms) {
            int m = idx_m[a];
            float inv[9];
            inv3x3(cell + m * 9, inv);
            float r0 = R[3 * a], r1 = R[3 * a + 1], r2 = R[3 * a + 2];
            // fractional coords in revolutions (2pi cancels)
            float s0 = inv[0] * r0 + inv[3] * r1 + inv[6] * r2;
            float s1 = inv[1] * r0 + inv[4] * r1 + inv[7] * r2;
            float s2 = inv[2] * r0 + inv[5] * r1 + inv[8] * r2;
            float qa = q[a];
            S4[a] = make_float4(s0, s1, s2, qa);
            QM[a] = make_float2(qa, __int_as_float(m));
            atomicAdd(&si[m & 63], qa * qa);
        }
        __syncthreads();
        if (tid < 64) SIpart[(size_t)tid * NAP + bid] = si[tid];   // plain store
    } else if (bid == NA) {
        int m = tid;
        if (m <= nmol) {
            int lo = 0, hi = natoms;
            while (lo < hi) {
                int mid = (lo + hi) >> 1;
                if (idx_m[mid] < m) lo = mid + 1; else hi = mid;
            }
            bounds[m] = lo;
        }
    } else if (bid == NA + 1) {
        if (tid == 0) { *cnt = 0; *ticket = 0; }
        __syncthreads();
        for (int k = tid; k < nk; k += 256) {
            float gx = kvecs[3 * k], gy = kvecs[3 * k + 1], gz = kvecs[3 * k + 2];
            bool pos = (gx > 0.5f) ||
                       (fabsf(gx) < 0.5f && (gy > 0.5f ||
                        (fabsf(gy) < 0.5f && gz > 0.5f)));
            if (pos) {
                int s = atomicAdd(cnt, 1);
                KH[s] = make_float4(gx, gy, gz, 0.0f);
            }
        }
        __syncthreads();
        int n = __hip_atomic_load(cnt, __ATOMIC_RELAXED, __HIP_MEMORY_SCOPE_AGENT);
        for (int s = n + tid; s < NK2; s += 256)
            KH[s] = make_float4(0.f, 0.f, 0.f, 0.f);   // zero pad slots
    } else {
        int zb = bid - (NA + 2);            // [0,64): zero QR/QI (+YRpad on zb==0)
        for (int t = tid; t < NK2; t += 256) {
            QR[zb * NK2 + t] = 0.0f;
            QI[zb * NK2 + t] = 0.0f;
        }
        if (zb == 0) for (int t = tid; t < 64 * 16; t += 256) YRpad[t] = 0.0f;
    }
}

// ---------------- mega: recip prelude + real loop + last-block finalize ----------------
__global__ __launch_bounds__(256, 8) void k_mega(const float4* __restrict__ S4,
                                                 const float4* __restrict__ KH,
                                                 const int* __restrict__ bounds,
                                                 float* __restrict__ QR,
                                                 float* __restrict__ QI,
                                                 const float* __restrict__ Rij,
                                                 const int* __restrict__ idx_i,
                                                 const int* __restrict__ idx_j,
                                                 const float2* __restrict__ QM,
                                                 float* __restrict__ YRpad,
                                                 const float* __restrict__ cell,
                                                 const int* __restrict__ cnt,
                                                 int* __restrict__ ticket,
                                                 const float* __restrict__ SIpart,
                                                 float* __restrict__ out,
                                                 int npairs, int NA) {
    __shared__ float acc[4][64];
    __shared__ int lastflag;
    int tid = threadIdx.x;
    int bid = blockIdx.x;
    int wave = tid >> 6;

    if (bid < NRB) {
        // ---- recip prelude: 2 half-k slots/thread, quarter-molecule atom range ----
        int m  = bid >> 2;
        int ac = bid & 3;
        int s0 = bounds[m], s1 = bounds[m + 1];
        int per = (s1 - s0 + 3) >> 2;
        int a0 = s0 + ac * per;
        int a1 = min(a0 + per, s1);
        float4 g0 = KH[tid];            // pad slots zero -> harmless
        float4 g1 = KH[tid + 256];
        float qr0 = 0.f, qi0 = 0.f, qr1 = 0.f, qi1 = 0.f;
#pragma unroll 4
        for (int t = a0; t < a1; ++t) {
            float4 s = S4[t];           // uniform address -> scalar load
            float ph0 = fmaf(g0.x, s.x, fmaf(g0.y, s.y, g0.z * s.z));
            float ph1 = fmaf(g1.x, s.x, fmaf(g1.y, s.y, g1.z * s.z));
            float sn0, cs0, sn1, cs1;
            sincos_rev(ph0, &sn0, &cs0);
            sincos_rev(ph1, &sn1, &cs1);
            qr0 = fmaf(s.w, cs0, qr0);
            qi0 = fmaf(s.w, sn0, qi0);
            qr1 = fmaf(s.w, cs1, qr1);
            qi1 = fmaf(s.w, sn1, qi1);
        }
        atomicAdd(&QR[m * NK2 + tid], qr0);
        atomicAdd(&QI[m * NK2 + tid], qi0);
        atomicAdd(&QR[m * NK2 + tid + 256], qr1);
        atomicAdd(&QI[m * NK2 + tid + 256], qi1);
    }

    // ---- real space: R8-exact structure (measured 89 us floor) ----
    acc[wave][tid & 63] = 0.0f;
    __syncthreads();
    const float sqa = 0.5477225575051661f;
    const float frcut = erfcf(sqa * CUTOFF_C) / CUTOFF_C;
    int nchunk = npairs >> 2;
    int stride = NREAL * 256;
    for (int c = bid * 256 + tid; c < nchunk; c += stride) {
        int p = c << 2;
        vint4 ii = *(const vint4*)(idx_i + p);
        vint4 jj = *(const vint4*)(idx_j + p);
        const vfloat4* r4 = (const vfloat4*)(Rij + 3 * p);
        vfloat4 ra = r4[0], rb = r4[1], rc = r4[2];
        float x0 = ra.x, y0 = ra.y, z0 = ra.z;
        float x1 = ra.w, y1 = rb.x, z1 = rb.y;
        float x2 = rb.z, y2 = rb.w, z2 = rc.x;
        float x3 = rc.y, y3 = rc.z, z3 = rc.w;
        float2 qi0 = QM[ii.x], qi1 = QM[ii.y], qi2 = QM[ii.z], qi3 = QM[ii.w];
        float2 qj0 = QM[jj.x], qj1 = QM[jj.y], qj2 = QM[jj.z], qj3 = QM[jj.w];
        float d0 = sqrtf(x0 * x0 + y0 * y0 + z0 * z0);
        float d1 = sqrtf(x1 * x1 + y1 * y1 + z1 * z1);
        float d2 = sqrtf(x2 * x2 + y2 * y2 + z2 * z2);
        float d3 = sqrtf(x3 * x3 + y3 * y3 + z3 * z3);
        if (d0 <= CUTOFF_C)
            atomicAdd(&acc[wave][__float_as_int(qi0.y) & 63],
                      qi0.x * qj0.x * (erfcf(sqa * d0) / d0 - frcut));
        if (d1 <= CUTOFF_C)
            atomicAdd(&acc[wave][__float_as_int(qi1.y) & 63],
                      qi1.x * qj1.x * (erfcf(sqa * d1) / d1 - frcut));
        if (d2 <= CUTOFF_C)
            atomicAdd(&acc[wave][__float_as_int(qi2.y) & 63],
                      qi2.x * qj2.x * (erfcf(sqa * d2) / d2 - frcut));
        if (d3 <= CUTOFF_C)
            atomicAdd(&acc[wave][__float_as_int(qi3.y) & 63],
                      qi3.x * qj3.x * (erfcf(sqa * d3) / d3 - frcut));
    }
    if (bid == 0 && tid == 0) {          // tail (npairs not multiple of 4)
        for (int p = (npairs >> 2) << 2; p < npairs; ++p) {
            float x = Rij[3 * p], y = Rij[3 * p + 1], z = Rij[3 * p + 2];
            float d = sqrtf(x * x + y * y + z * z);
            if (d <= CUTOFF_C) {
                float2 qi = QM[idx_i[p]];
                float2 qj = QM[idx_j[p]];
                atomicAdd(&acc[0][__float_as_int(qi.y) & 63],
                          qi.x * qj.x * (erfcf(sqa * d) / d - frcut));
            }
        }
    }
    __syncthreads();
    if (tid < 64) {
        float v = acc[0][tid] + acc[1][tid] + acc[2][tid] + acc[3][tid];
        atomicAdd(&YRpad[tid * 16], v);
    }

    // ---- ticket: last block to finish does the finalize ----
    __syncthreads();
    __threadfence();                      // drain/make visible all our global atomics
    if (tid == 0) {
        int t = atomicAdd(ticket, 1);
        lastflag = (t == NREAL - 1) ? 1 : 0;
    }
    __syncthreads();
    if (!lastflag) return;
    __threadfence();                      // acquire: see all other blocks' atomics

    // finalize: wave w handles molecules w, w+4, ... (16 per wave); lanes over k
    int lane = tid & 63;
    int nhalf = cnt[0];
    const float self_c = 0.30901936161855375f;  // sqrt(0.3/pi)
    for (int m = wave; m < 64; m += 4) {
        float inv[9];
        float det = inv3x3(cell + m * 9, inv);
        float a2 = 0.0f, si = 0.0f;
        for (int k = lane; k < nhalf; k += 64) {
            float4 g = KH[k];
            float kv0 = TWO_PI_C * (g.x * inv[0] + g.y * inv[1] + g.z * inv[2]);
            float kv1 = TWO_PI_C * (g.x * inv[3] + g.y * inv[4] + g.z * inv[5]);
            float kv2 = TWO_PI_C * (g.x * inv[6] + g.y * inv[7] + g.z * inv[8]);
            float ksq = kv0 * kv0 + kv1 * kv1 + kv2 * kv2;
            float qr = load_agent(&QR[m * NK2 + k]);
            float qi = load_agent(&QI[m * NK2 + k]);
            a2 += (qr * qr + qi * qi) * __expf(-0.25f / ALPHA_C * ksq) / ksq;
        }
        for (int b = lane; b < NA; b += 64) si += SIpart[(size_t)m * NAP + b];
#pragma unroll
        for (int off = 32; off > 0; off >>= 1) {
            a2 += __shfl_down(a2, off, 64);
            si += __shfl_down(si, off, 64);
        }
        if (lane == 0) {
            float yreal = load_agent(&YRpad[m * 16]);
            float pref = TWO_PI_C / fabsf(det);
            out[m] = 0.5f * KE_C * yreal + KE_C * (pref * 2.0f * a2 - self_c * si);
        }
    }
}

extern "C" void kernel_launch(void* const* d_in, const int* in_sizes, int n_in,
                              void* d_out, int out_size, void* d_ws, size_t ws_size,
                              hipStream_t stream) {
    const float* q     = (const float*)d_in[0];
    const float* Rij   = (const float*)d_in[1];
    const float* R     = (const float*)d_in[2];
    const float* cell  = (const float*)d_in[3];
    const float* kvecs = (const float*)d_in[4];
    const int*   idx_m = (const int*)d_in[5];
    const int*   idx_i = (const int*)d_in[6];
    const int*   idx_j = (const int*)d_in[7];

    int natoms = in_sizes[0];
    int npairs = in_sizes[1] / 3;
    int nmol   = in_sizes[3] / 9;
    int nk     = in_sizes[4] / 3;
    float* out = (float*)d_out;

    // workspace layout (float offsets; S4/KH 16B-, QM 8B-aligned)
    float*  W      = (float*)d_ws;
    int*    bounds = (int*)W;                                   // 80 ints
    float4* S4     = (float4*)(W + 80);                         // natoms float4
    float2* QM     = (float2*)(W + 80 + 4 * (size_t)natoms);    // natoms float2
    size_t  off    = 80 + 6 * (size_t)natoms;
    off = (off + 3) & ~(size_t)3;                               // 16B align
    float4* KH     = (float4*)(W + off);                        // NK2 float4
    float*  QR     = W + off + 4 * NK2;                         // nmol*NK2
    float*  QI     = QR + (size_t)nmol * NK2;                   // nmol*NK2
    float*  YRpad  = QI + (size_t)nmol * NK2;                   // 64*16
    float*  SIpart = YRpad + 64 * 16;                           // 64*NAP
    int*    cnt    = (int*)(SIpart + 64 * NAP);                 // 1
    int*    ticket = cnt + 1;                                   // 1

    int NA = (natoms + 255) / 256;
    k_setup<<<NA + 2 + 64, 256, 0, stream>>>(R, q, idx_m, cell, kvecs, S4, QM,
                                             SIpart, bounds, KH, cnt, ticket,
                                             QR, QI, YRpad, natoms, nmol, nk, NA);
    k_mega <<<NREAL, 256, 0, stream>>>(S4, KH, bounds, QR, QI,
                                       Rij, idx_i, idx_j, QM, YRpad,
                                       cell, cnt, ticket, SIpart, out,
                                       npairs, NA);
}

// Round 14
// 217.976 us; speedup vs baseline: 2.8236x; 2.8236x over previous
//
#include <hip/hip_runtime.h>
#include <math.h>

#define KE_C     14.3996f
#define ALPHA_C  0.3f
#define CUTOFF_C 10.0f
#define TWO_PI_C 6.283185307179586f
#define NK2      512           // padded half-k slot count (510 real)
#define NRB      256           // recip prelude blocks (64 mol x 4 chunks)
#define NREAL    2048          // mega grid (8 blocks/CU)
#define NAP      400           // SIpart stride (>= NA)

typedef float vfloat4 __attribute__((ext_vector_type(4)));
typedef int   vint4   __attribute__((ext_vector_type(4)));

__device__ __forceinline__ void sincos_rev(float x, float* s, float* c) {
    float f = __builtin_amdgcn_fractf(x);
    *s = __builtin_amdgcn_sinf(f);
    *c = __builtin_amdgcn_cosf(f);
}

__device__ __forceinline__ float inv3x3(const float* c, float* inv) {
    float a00 = c[0], a01 = c[1], a02 = c[2];
    float a10 = c[3], a11 = c[4], a12 = c[5];
    float a20 = c[6], a21 = c[7], a22 = c[8];
    float det = a00 * (a11 * a22 - a12 * a21)
              - a01 * (a10 * a22 - a12 * a20)
              + a02 * (a10 * a21 - a11 * a20);
    float id = 1.0f / det;
    inv[0] = (a11 * a22 - a12 * a21) * id;
    inv[1] = (a02 * a21 - a01 * a22) * id;
    inv[2] = (a01 * a12 - a02 * a11) * id;
    inv[3] = (a12 * a20 - a10 * a22) * id;
    inv[4] = (a00 * a22 - a02 * a20) * id;
    inv[5] = (a02 * a10 - a00 * a12) * id;
    inv[6] = (a10 * a21 - a11 * a20) * id;
    inv[7] = (a01 * a20 - a00 * a21) * id;
    inv[8] = (a00 * a11 - a01 * a10) * id;
    return det;
}

// ---------------- setup: atoms + bounds + half-k + zeroing (no memset needed) ----------------
// blocks [0,NA): per-atom S4/QM + SIpart partials (no global atomics, no pre-zero)
// block NA: molecule bounds; block NA+1: half-k compaction (self-zeroing cnt + pads)
// blocks [NA+2, NA+2+64): zero QR/QI/YRpad
__global__ __launch_bounds__(256) void k_setup(const float* __restrict__ R,
                                               const float* __restrict__ q,
                                               const int* __restrict__ idx_m,
                                               const float* __restrict__ cell,
                                               const float* __restrict__ kvecs,
                                               float4* __restrict__ S4,
                                               float2* __restrict__ QM,
                                               float* __restrict__ SIpart,
                                               int* __restrict__ bounds,
                                               float4* __restrict__ KH,
                                               int* __restrict__ cnt,
                                               float* __restrict__ QR,
                                               float* __restrict__ QI,
                                               float* __restrict__ YRpad,
                                               int natoms, int nmol, int nk, int NA) {
    int bid = blockIdx.x;
    int tid = threadIdx.x;
    if (bid < NA) {
        __shared__ float si[64];
        if (tid < 64) si[tid] = 0.0f;
        __syncthreads();
        int a = bid * 256 + tid;
        if (a < natoms) {
            int m = idx_m[a];
            float inv[9];
            inv3x3(cell + m * 9, inv);
            float r0 = R[3 * a], r1 = R[3 * a + 1], r2 = R[3 * a + 2];
            // fractional coords in revolutions (2pi cancels)
            float s0 = inv[0] * r0 + inv[3] * r1 + inv[6] * r2;
            float s1 = inv[1] * r0 + inv[4] * r1 + inv[7] * r2;
            float s2 = inv[2] * r0 + inv[5] * r1 + inv[8] * r2;
            float qa = q[a];
            S4[a] = make_float4(s0, s1, s2, qa);
            QM[a] = make_float2(qa, __int_as_float(m));
            atomicAdd(&si[m & 63], qa * qa);
        }
        __syncthreads();
        if (tid < 64) SIpart[(size_t)tid * NAP + bid] = si[tid];   // plain store
    } else if (bid == NA) {
        int m = tid;
        if (m <= nmol) {
            int lo = 0, hi = natoms;
            while (lo < hi) {
                int mid = (lo + hi) >> 1;
                if (idx_m[mid] < m) lo = mid + 1; else hi = mid;
            }
            bounds[m] = lo;
        }
    } else if (bid == NA + 1) {
        if (tid == 0) *cnt = 0;
        __syncthreads();
        for (int k = tid; k < nk; k += 256) {
            float gx = kvecs[3 * k], gy = kvecs[3 * k + 1], gz = kvecs[3 * k + 2];
            bool pos = (gx > 0.5f) ||
                       (fabsf(gx) < 0.5f && (gy > 0.5f ||
                        (fabsf(gy) < 0.5f && gz > 0.5f)));
            if (pos) {
                int s = atomicAdd(cnt, 1);
                KH[s] = make_float4(gx, gy, gz, 0.0f);
            }
        }
        __syncthreads();
        int n = __hip_atomic_load(cnt, __ATOMIC_RELAXED, __HIP_MEMORY_SCOPE_AGENT);
        for (int s = n + tid; s < NK2; s += 256)
            KH[s] = make_float4(0.f, 0.f, 0.f, 0.f);   // zero pad slots
    } else {
        int zb = bid - (NA + 2);            // [0,64): zero QR/QI (+YRpad on zb==0)
        for (int t = tid; t < NK2; t += 256) {
            QR[zb * NK2 + t] = 0.0f;
            QI[zb * NK2 + t] = 0.0f;
        }
        if (zb == 0) for (int t = tid; t < 64 * 16; t += 256) YRpad[t] = 0.0f;
    }
}

// ---------------- mega: recip prelude (blocks 0..NRB) + R8-exact real loop (all) ----------
__global__ __launch_bounds__(256, 8) void k_mega(const float4* __restrict__ S4,
                                                 const float4* __restrict__ KH,
                                                 const int* __restrict__ bounds,
                                                 float* __restrict__ QR,
                                                 float* __restrict__ QI,
                                                 const float* __restrict__ Rij,
                                                 const int* __restrict__ idx_i,
                                                 const int* __restrict__ idx_j,
                                                 const float2* __restrict__ QM,
                                                 float* __restrict__ YRpad, int npairs) {
    __shared__ float acc[4][64];
    int tid = threadIdx.x;
    int bid = blockIdx.x;
    int wave = tid >> 6;

    if (bid < NRB) {
        // ---- recip prelude: 2 half-k slots/thread, quarter-molecule atom range ----
        int m  = bid >> 2;
        int ac = bid & 3;
        int s0 = bounds[m], s1 = bounds[m + 1];
        int per = (s1 - s0 + 3) >> 2;
        int a0 = s0 + ac * per;
        int a1 = min(a0 + per, s1);
        float4 g0 = KH[tid];            // pad slots zero -> harmless
        float4 g1 = KH[tid + 256];
        float qr0 = 0.f, qi0 = 0.f, qr1 = 0.f, qi1 = 0.f;
#pragma unroll 4
        for (int t = a0; t < a1; ++t) {
            float4 s = S4[t];           // uniform address -> scalar load
            float ph0 = fmaf(g0.x, s.x, fmaf(g0.y, s.y, g0.z * s.z));
            float ph1 = fmaf(g1.x, s.x, fmaf(g1.y, s.y, g1.z * s.z));
            float sn0, cs0, sn1, cs1;
            sincos_rev(ph0, &sn0, &cs0);
            sincos_rev(ph1, &sn1, &cs1);
            qr0 = fmaf(s.w, cs0, qr0);
            qi0 = fmaf(s.w, sn0, qi0);
            qr1 = fmaf(s.w, cs1, qr1);
            qi1 = fmaf(s.w, sn1, qi1);
        }
        atomicAdd(&QR[m * NK2 + tid], qr0);
        atomicAdd(&QI[m * NK2 + tid], qi0);
        atomicAdd(&QR[m * NK2 + tid + 256], qr1);
        atomicAdd(&QI[m * NK2 + tid + 256], qi1);
    }

    // ---- real space: R8-exact structure (measured 89 us floor) ----
    acc[wave][tid & 63] = 0.0f;
    __syncthreads();
    const float sqa = 0.5477225575051661f;
    const float frcut = erfcf(sqa * CUTOFF_C) / CUTOFF_C;
    int nchunk = npairs >> 2;
    int stride = NREAL * 256;
    for (int c = bid * 256 + tid; c < nchunk; c += stride) {
        int p = c << 2;
        vint4 ii = *(const vint4*)(idx_i + p);
        vint4 jj = *(const vint4*)(idx_j + p);
        const vfloat4* r4 = (const vfloat4*)(Rij + 3 * p);
        vfloat4 ra = r4[0], rb = r4[1], rc = r4[2];
        float x0 = ra.x, y0 = ra.y, z0 = ra.z;
        float x1 = ra.w, y1 = rb.x, z1 = rb.y;
        float x2 = rb.z, y2 = rb.w, z2 = rc.x;
        float x3 = rc.y, y3 = rc.z, z3 = rc.w;
        float2 qi0 = QM[ii.x], qi1 = QM[ii.y], qi2 = QM[ii.z], qi3 = QM[ii.w];
        float2 qj0 = QM[jj.x], qj1 = QM[jj.y], qj2 = QM[jj.z], qj3 = QM[jj.w];
        float d0 = sqrtf(x0 * x0 + y0 * y0 + z0 * z0);
        float d1 = sqrtf(x1 * x1 + y1 * y1 + z1 * z1);
        float d2 = sqrtf(x2 * x2 + y2 * y2 + z2 * z2);
        float d3 = sqrtf(x3 * x3 + y3 * y3 + z3 * z3);
        if (d0 <= CUTOFF_C)
            atomicAdd(&acc[wave][__float_as_int(qi0.y) & 63],
                      qi0.x * qj0.x * (erfcf(sqa * d0) / d0 - frcut));
        if (d1 <= CUTOFF_C)
            atomicAdd(&acc[wave][__float_as_int(qi1.y) & 63],
                      qi1.x * qj1.x * (erfcf(sqa * d1) / d1 - frcut));
        if (d2 <= CUTOFF_C)
            atomicAdd(&acc[wave][__float_as_int(qi2.y) & 63],
                      qi2.x * qj2.x * (erfcf(sqa * d2) / d2 - frcut));
        if (d3 <= CUTOFF_C)
            atomicAdd(&acc[wave][__float_as_int(qi3.y) & 63],
                      qi3.x * qj3.x * (erfcf(sqa * d3) / d3 - frcut));
    }
    if (bid == 0 && tid == 0) {          // tail (npairs not multiple of 4)
        for (int p = (npairs >> 2) << 2; p < npairs; ++p) {
            float x = Rij[3 * p], y = Rij[3 * p + 1], z = Rij[3 * p + 2];
            float d = sqrtf(x * x + y * y + z * z);
            if (d <= CUTOFF_C) {
                float2 qi = QM[idx_i[p]];
                float2 qj = QM[idx_j[p]];
                atomicAdd(&acc[0][__float_as_int(qi.y) & 63],
                          qi.x * qj.x * (erfcf(sqa * d) / d - frcut));
            }
        }
    }
    __syncthreads();
    if (tid < 64) {
        float v = acc[0][tid] + acc[1][tid] + acc[2][tid] + acc[3][tid];
        atomicAdd(&YRpad[tid * 16], v);
    }
}

// ---------------- finalize per molecule (half-space k x2; SIpart reduction) --------------
__global__ __launch_bounds__(256) void k_final(const float4* __restrict__ KH,
                                               const int* __restrict__ cnt,
                                               const float* __restrict__ cell,
                                               const float* __restrict__ QR,
                                               const float* __restrict__ QI,
                                               const float* __restrict__ YRpad,
                                               const float* __restrict__ SIpart,
                                               float* __restrict__ out, int NA) {
    int m = blockIdx.x;
    int tid = threadIdx.x;
    __shared__ float wsum[4], wsi[4];
    float inv[9];
    float det = inv3x3(cell + m * 9, inv);
    int nhalf = cnt[0];
    float acc = 0.0f, si = 0.0f;
    for (int k = tid; k < nhalf; k += 256) {
        float4 g = KH[k];
        float kv0 = TWO_PI_C * (g.x * inv[0] + g.y * inv[1] + g.z * inv[2]);
        float kv1 = TWO_PI_C * (g.x * inv[3] + g.y * inv[4] + g.z * inv[5]);
        float kv2 = TWO_PI_C * (g.x * inv[6] + g.y * inv[7] + g.z * inv[8]);
        float ksq = kv0 * kv0 + kv1 * kv1 + kv2 * kv2;
        float qr = QR[m * NK2 + k], qi = QI[m * NK2 + k];
        acc += (qr * qr + qi * qi) * __expf(-0.25f / ALPHA_C * ksq) / ksq;
    }
    for (int b = tid; b < NA; b += 256) si += SIpart[(size_t)m * NAP + b];
#pragma unroll
    for (int off = 32; off > 0; off >>= 1) {
        acc += __shfl_down(acc, off, 64);
        si  += __shfl_down(si,  off, 64);
    }
    if ((tid & 63) == 0) { wsum[tid >> 6] = acc; wsi[tid >> 6] = si; }
    __syncthreads();
    if (tid == 0) {
        float s  = 2.0f * (wsum[0] + wsum[1] + wsum[2] + wsum[3]);   // +g/-g symmetry
        float st = wsi[0] + wsi[1] + wsi[2] + wsi[3];
        float pref = TWO_PI_C / fabsf(det);
        float self_c = sqrtf(ALPHA_C / 3.14159265358979323846f);
        out[m] = 0.5f * KE_C * YRpad[m * 16] + KE_C * (pref * s - self_c * st);
    }
}

extern "C" void kernel_launch(void* const* d_in, const int* in_sizes, int n_in,
                              void* d_out, int out_size, void* d_ws, size_t ws_size,
                              hipStream_t stream) {
    const float* q     = (const float*)d_in[0];
    const float* Rij   = (const float*)d_in[1];
    const float* R     = (const float*)d_in[2];
    const float* cell  = (const float*)d_in[3];
    const float* kvecs = (const float*)d_in[4];
    const int*   idx_m = (const int*)d_in[5];
    const int*   idx_i = (const int*)d_in[6];
    const int*   idx_j = (const int*)d_in[7];

    int natoms = in_sizes[0];
    int npairs = in_sizes[1] / 3;
    int nmol   = in_sizes[3] / 9;
    int nk     = in_sizes[4] / 3;
    float* out = (float*)d_out;

    // workspace layout (float offsets; S4/KH 16B-, QM 8B-aligned)
    float*  W      = (float*)d_ws;
    int*    bounds = (int*)W;                                   // 80 ints
    float4* S4     = (float4*)(W + 80);                         // natoms float4
    float2* QM     = (float2*)(W + 80 + 4 * (size_t)natoms);    // natoms float2
    size_t  off    = 80 + 6 * (size_t)natoms;
    off = (off + 3) & ~(size_t)3;                               // 16B align
    float4* KH     = (float4*)(W + off);                        // NK2 float4
    float*  QR     = W + off + 4 * NK2;                         // nmol*NK2
    float*  QI     = QR + (size_t)nmol * NK2;                   // nmol*NK2
    float*  YRpad  = QI + (size_t)nmol * NK2;                   // 64*16
    float*  SIpart = YRpad + 64 * 16;                           // 64*NAP
    int*    cnt    = (int*)(SIpart + 64 * NAP);                 // 4

    int NA = (natoms + 255) / 256;
    k_setup<<<NA + 2 + 64, 256, 0, stream>>>(R, q, idx_m, cell, kvecs, S4, QM,
                                             SIpart, bounds, KH, cnt, QR, QI,
                                             YRpad, natoms, nmol, nk, NA);
    k_mega <<<NREAL, 256, 0, stream>>>(S4, KH, bounds, QR, QI,
                                       Rij, idx_i, idx_j, QM, YRpad, npairs);
    k_final<<<nmol, 256, 0, stream>>>(KH, cnt, cell, QR, QI, YRpad, SIpart, out, NA);
}